// Round 14
// baseline (3141.486 us; speedup 1.0000x reference)
//
#include <hip/hip_runtime.h>

#define L  8192
#define E  300
#define H  256
#define FH 1024
#define T  5

#define NCH 64     // chunks per direction
#define CHL 128    // owned steps per chunk
#define WUP 48     // warm-up steps (0.5^48 ~ 4e-15 << f32 half-ulp: bit-exact)

typedef float f32x4 __attribute__((ext_vector_type(4)));

// ---- workspace layout (float offsets unless noted) ----
#define XP_OFF   0u           // [2][L][FH]  f32
#define HS_OFF   16777216u    // [2][L][H]   f32  (canary-init each call; polled)
#define EM_OFF   20971520u    // [L][8] f32
#define PC_OFF   21037312u    // [64][32] chunk max-plus matrices (25 used)
#define SB_OFF   21039360u    // [65][8] boundary scores
#define LAST_OFF 21039880u    // int: last tag
#define BP_BYTE  84159552u    // byte offset: [L][5] u8 backpointers
#define F_BYTE   84200512u    // byte offset: [64][8] u8 chunk composition maps
#define TB_BYTE  84201024u    // byte offset: [64] int boundary tags
#define WR_BYTE  84205568u    // byte offset: [128 chunks][WUP][256] f32 warm rings (canary-init)

// 8-lane sum reduction, pure VALU via DPP.
__device__ __forceinline__ float red8(float x) {
  x += __int_as_float(__builtin_amdgcn_update_dpp(0, __float_as_int(x), 0xB1, 0xF, 0xF, true));  // xor 1
  x += __int_as_float(__builtin_amdgcn_update_dpp(0, __float_as_int(x), 0x4E, 0xF, 0xF, true));  // xor 2
  x += __int_as_float(__builtin_amdgcn_update_dpp(0, __float_as_int(x), 0x141, 0xF, 0xF, true)); // half-mirror
  return x;
}

// ---------------------------------------------------------------------------
// Kernel 1: xproj[d][t][r] = bias[d][r] + embed[sent[t]] . W_ih[d][r]
// t-tile 64 (halves W_ih re-streaming vs 32). grid (128, 4), block 256,
// LDS 78KB (2 blocks/CU). acc 2x64 = 128 f32/thread.
// ---------------------------------------------------------------------------
__global__ __launch_bounds__(256) void k_xproj(
    const int* __restrict__ sent, const float* __restrict__ embed,
    const float* __restrict__ wihf, const float* __restrict__ bf,
    const float* __restrict__ wihb, const float* __restrict__ bb,
    float* __restrict__ xp)
{
  __shared__ float xl[64][304];
  __shared__ int sl[64];
  const int tid = threadIdx.x;
  const int t0 = blockIdx.x * 64;
  const int d = blockIdx.y >> 1, rh = blockIdx.y & 1;
  const int r1 = rh * 256 + tid;     // 0..511
  const int r2 = r1 + 512;           // 512..1023
  if (tid < 64) sl[tid] = sent[t0 + tid];
  __syncthreads();
  for (int tt = 0; tt < 64; ++tt) {
    const float* erow = embed + (size_t)sl[tt] * 300;
    for (int kk = tid; kk < 300; kk += 256) xl[tt][kk] = erow[kk];
  }
  __syncthreads();
  const float* wih  = d ? wihb : wihf;
  const float* bias = d ? bb : bf;
  const float4* wra = (const float4*)(wih + (size_t)r1 * 300);
  const float4* wrb = (const float4*)(wih + (size_t)r2 * 300);
  float acca[64], accb[64];
#pragma unroll
  for (int tt = 0; tt < 64; ++tt) { acca[tt] = 0.f; accb[tt] = 0.f; }
  for (int k4 = 0; k4 < 75; ++k4) {
    const float4 wa = wra[k4];
    const float4 wb = wrb[k4];
#pragma unroll
    for (int tt = 0; tt < 64; ++tt) {
      const float4 xv = *(const float4*)&xl[tt][k4 * 4];
      acca[tt] = fmaf(wa.x, xv.x, fmaf(wa.y, xv.y, fmaf(wa.z, xv.z, fmaf(wa.w, xv.w, acca[tt]))));
      accb[tt] = fmaf(wb.x, xv.x, fmaf(wb.y, xv.y, fmaf(wb.z, xv.z, fmaf(wb.w, xv.w, accb[tt]))));
    }
  }
  const float bv1 = bias[r1], bv2 = bias[r2];
#pragma unroll
  for (int tt = 0; tt < 64; ++tt) {
    xp[((size_t)d * L + (t0 + tt)) * FH + r1] = acca[tt] + bv1;
    xp[((size_t)d * L + (t0 + tt)) * FH + r2] = accb[tt] + bv2;
  }
}

// ---------------------------------------------------------------------------
// Kernel 2: chunked bidirectional LSTM, 4-chunk interleave, poll-at-ROUND-START.
// 32 groups x 4 slice-blocks (bid = gid + 32*g -> same XCD), 128 blocks.
// NEW vs R13: duty wave ci (= wave ci) polls+publishes chunk ci at the START
// of each round, BEFORE any compute -- the four polls overlap fully across
// waves (R8's duty waves polled after waiting earlier flags, so they still
// serialized; this is the untested configuration). lh deepened to 4 buffers
// so the reuse guard (ldone >= 8*(sc-3)) virtually never blocks a publisher.
// Everything else (canary protocol, sc0 stores, WUP=48, swizzled LDS) = R13.
// ---------------------------------------------------------------------------
__global__ __launch_bounds__(512, 2) void k_lstm(
    const float* __restrict__ xp,
    const float* __restrict__ whhf, const float* __restrict__ whhb,
    const float* __restrict__ h0, const float* __restrict__ c0,
    float* __restrict__ hs, float* __restrict__ wring)
{
  const int bid = blockIdx.x;
  const int gid = bid & 31;        // group: bid%8 == gid%8 for all 4 slices
  const int g   = bid >> 5;        // slice 0..3: owns units [g*64, g*64+64)
  const int d = gid >> 4, p = gid & 15;
  const int kA = 4 * p, kB = 4 * p + 1, kC = 4 * p + 2, kD = 4 * p + 3;
  const int tid = threadIdx.x;
  const int l = tid & 63, w = tid >> 6;
  const int ul = w * 8 + (l >> 3);   // unit within block 0..63
  const int j  = g * 64 + ul;        // unit 0..255
  const int kq = l & 7;              // this thread covers h[kq*32..+32)
  const float* whh = d ? whhb : whhf;

  // 128 weight floats per thread, pinned via opaque asm.
  float wgf[4][32];
#pragma unroll
  for (int gt = 0; gt < 4; ++gt) {
    const float* base = whh + (size_t)(gt * 256 + j) * 256 + kq * 32;
#pragma unroll
    for (int i = 0; i < 8; ++i) {
      float4 v = *(const float4*)(base + 4 * i);
      asm volatile("" : "+v"(v.x), "+v"(v.y), "+v"(v.z), "+v"(v.w));
      wgf[gt][4 * i + 0] = v.x; wgf[gt][4 * i + 1] = v.y;
      wgf[gt][4 * i + 2] = v.z; wgf[gt][4 * i + 3] = v.w;
    }
  }

  // Per-chunk LDS h broadcast: 4-deep buffered, XOR-swizzled; flag + done-ctr.
  __shared__ float lh[4][4][256];
  __shared__ int lfl[4];
  __shared__ int ldone[4];
  if (tid < 4) { lfl[tid] = 0; ldone[tid] = 0; }
  __syncthreads();

  const bool noWA = (d == 0 && kA == 0);
  const bool noWD = (d == 1 && kD == NCH - 1);
  float cA = noWA ? c0[d * 256 + j] : 0.f;
  float cB = 0.f;
  float cC = 0.f;
  float cD = noWD ? c0[d * 256 + j] : 0.f;

  float* ringA = wring + (size_t)(d * NCH + kA) * (WUP * 256);
  float* ringB = wring + (size_t)(d * NCH + kB) * (WUP * 256);
  float* ringC = wring + (size_t)(d * NCH + kC) * (WUP * 256);
  float* ringD = wring + (size_t)(d * NCH + kD) * (WUP * 256);

  bool slow = false;
  const int rr = l >> 3, cc = l & 7;   // publish swizzle coords

  // Duty wave: acquire h(sc-1) for chunk ci and publish to LDS. Runs at
  // round start, before any compute -- all 4 duty polls overlap.
  auto duty_acquire = [&](int ci, int kch, bool noW, float* ring, int r) {
    const int Wc = noW ? 0 : WUP;
    const int sc = noW ? (r - WUP) : r;
    if (sc < 1 || sc >= Wc + CHL) return;
    if (sc >= 4) {   // 4-deep buffer reuse guard (rarely blocks)
      while (__hip_atomic_load(&ldone[ci], __ATOMIC_RELAXED,
                               __HIP_MEMORY_SCOPE_WORKGROUP) < 8 * (sc - 3)) {}
    }
    const float* src;
    if (sc - 1 < Wc) {
      src = ring + (size_t)(sc - 1) * 256;
    } else {
      const int tp = d ? (kch * CHL + CHL - 1 + Wc - (sc - 1))
                       : (kch * CHL - Wc + (sc - 1));
      src = hs + ((size_t)d * L + tp) * H;
    }
    const float* myp = src + 4 * l;
    f32x4 hx;
    int iters = 0;
    for (;;) {
      if (!slow) {
        asm volatile("global_load_dwordx4 %0, %1, off sc0\n\t"
                     "s_waitcnt vmcnt(0)"
                     : "=v"(hx) : "v"(myp) : "memory");
      } else {
        asm volatile("s_sleep 8\n\t"
                     "global_load_dwordx4 %0, %1, off sc0 sc1\n\t"
                     "s_waitcnt vmcnt(0)"
                     : "=v"(hx) : "v"(myp) : "memory");
      }
      const unsigned u0 = __float_as_uint(hx.x), u1 = __float_as_uint(hx.y);
      const unsigned u2 = __float_as_uint(hx.z), u3 = __float_as_uint(hx.w);
      const bool bad = (u0 == 0xFFFFFFFFu) | (u1 == 0xFFFFFFFFu) |
                       (u2 == 0xFFFFFFFFu) | (u3 == 0xFFFFFFFFu);
      if (!__any(bad)) break;
      if (!slow && ++iters > 4096) slow = true;   // sticky fallback (G16)
    }
    *(f32x4*)&lh[ci][sc & 3][rr * 32 + 4 * (cc ^ rr)] = hx;
    asm volatile("s_waitcnt lgkmcnt(0)" ::: "memory");
    __hip_atomic_store(&lfl[ci], sc, __ATOMIC_RELAXED, __HIP_MEMORY_SCOPE_WORKGROUP);
  };

  auto chunk_compute = [&](int ci, int kch, bool noW, float* ring, float& cst, int r) {
    const int Wc = noW ? 0 : WUP;
    const int sc = noW ? (r - WUP) : r;
    if (sc < 0 || sc >= Wc + CHL) return;
    const int t = d ? (kch * CHL + CHL - 1 + Wc - sc)
                    : (kch * CHL - Wc + sc);
    // x loads issue now; they drain under the flag spin (or the duty poll)
    const float* xr = xp + ((size_t)d * L + t) * FH;
    const float x0 = xr[j], x1 = xr[256 + j], x2 = xr[512 + j], x3 = xr[768 + j];

    float a0 = 0.f, a1 = 0.f, a2 = 0.f, a3 = 0.f;
    if (sc == 0) {
      if (noW) {     // true h0: stable input, no sync needed
        const float* hp = h0 + d * 256 + kq * 32;
#pragma unroll
        for (int ii = 0; ii < 8; ++ii) {
          const f32x4 hc = *(const f32x4*)(hp + 4 * ii);
#pragma unroll
          for (int dd = 0; dd < 4; ++dd) {
            const float hv = hc[dd];
            a0 = fmaf(wgf[0][4 * ii + dd], hv, a0);
            a1 = fmaf(wgf[1][4 * ii + dd], hv, a1);
            a2 = fmaf(wgf[2][4 * ii + dd], hv, a2);
            a3 = fmaf(wgf[3][4 * ii + dd], hv, a3);
          }
        }
      }
      // else: zero-boot warm start, h == 0 -> a stays 0.
    } else {
      if (w != ci) {   // duty wave already has its publish done
        while (__hip_atomic_load(&lfl[ci], __ATOMIC_RELAXED,
                                 __HIP_MEMORY_SCOPE_WORKGROUP) < sc) {}
      }
      // ---- conflict-free swizzled LDS reads + 128 fma ----
#pragma unroll
      for (int ii = 0; ii < 8; ++ii) {
        const f32x4 hc = *(const f32x4*)&lh[ci][sc & 3][kq * 32 + 4 * (ii ^ kq)];
#pragma unroll
        for (int dd = 0; dd < 4; ++dd) {
          const float hv = hc[dd];
          a0 = fmaf(wgf[0][4 * ii + dd], hv, a0);
          a1 = fmaf(wgf[1][4 * ii + dd], hv, a1);
          a2 = fmaf(wgf[2][4 * ii + dd], hv, a2);
          a3 = fmaf(wgf[3][4 * ii + dd], hv, a3);
        }
      }
    }
    a0 = red8(a0); a1 = red8(a1); a2 = red8(a2); a3 = red8(a3);

    const float gi = x0 + a0, gf = x1 + a1, gc = x2 + a2, go = x3 + a3;
    const float ig = 1.f / (1.f + __expf(-gi));
    const float fg = 1.f / (1.f + __expf(-gf));
    const float cg = 1.f - 2.f / (1.f + __expf(2.f * gc));   // tanh
    const float og = 1.f / (1.f + __expf(-go));
    cst = fg * cst + ig * cg;
    const float hn = og * (1.f - 2.f / (1.f + __expf(2.f * cst)));
    if (kq == 0) {
      float* dst = (sc < Wc) ? (ring + (size_t)sc * 256 + j)
                             : (hs + ((size_t)d * L + t) * H + j);
      // sc0 store: write directed at L2 (the handoff coherence point)
      asm volatile("global_store_dword %0, %1, off sc0"
                   :: "v"(dst), "v"(hn) : "memory");
    }
    if (l == 0)
      __hip_atomic_fetch_add(&ldone[ci], 1, __ATOMIC_RELAXED, __HIP_MEMORY_SCOPE_WORKGROUP);
  };

  for (int r = 0; r < WUP + CHL; ++r) {
    // ---- round-start duty polls: 4 waves poll 4 chunks CONCURRENTLY ----
    if      (w == 0) duty_acquire(0, kA, noWA, ringA, r);
    else if (w == 1) duty_acquire(1, kB, false, ringB, r);
    else if (w == 2) duty_acquire(2, kC, false, ringC, r);
    else if (w == 3) duty_acquire(3, kD, noWD, ringD, r);
    // ---- compute phase: all waves, chunks in order ----
    chunk_compute(0, kA, noWA, ringA, cA, r);
    chunk_compute(1, kB, false, ringB, cB, r);
    chunk_compute(2, kC, false, ringC, cC, r);
    chunk_compute(3, kD, noWD, ringD, cD, r);
    if ((r & 63) == 63) __threadfence();   // rare MALL visibility (G16 fallback)
  }
}

// ---------------------------------------------------------------------------
// Kernel 3: emission[t][tag]
// ---------------------------------------------------------------------------
__global__ __launch_bounds__(256) void k_emis(
    const float* __restrict__ hs, const float* __restrict__ wout,
    const float* __restrict__ bout, float* __restrict__ em)
{
  const int tid = threadIdx.x, l = tid & 63;
  const int t = blockIdx.x * 4 + (tid >> 6);
  const float4 hf = ((const float4*)(hs + (size_t)t * H))[l];
  const float4 hb = ((const float4*)(hs + (size_t)L * H + (size_t)t * H))[l];
  const float4* w4 = (const float4*)wout;
  float s[5];
#pragma unroll
  for (int tag = 0; tag < 5; ++tag) {
    const float4 wf = w4[tag * 128 + l];
    const float4 wb = w4[tag * 128 + 64 + l];
    float p = hf.x * wf.x + hf.y * wf.y + hf.z * wf.z + hf.w * wf.w
            + hb.x * wb.x + hb.y * wb.y + hb.z * wb.z + hb.w * wb.w;
#pragma unroll
    for (int m = 1; m < 64; m <<= 1) p += __shfl_xor(p, m, 64);
    s[tag] = p;
  }
  if (l == 0) {
#pragma unroll
    for (int tag = 0; tag < 5; ++tag) em[(size_t)t * 8 + tag] = s[tag] + bout[tag];
  }
}

// ---------------------------------------------------------------------------
// Viterbi, chunked (64 chunks x 128 transitions), max-plus associativity.
// ---------------------------------------------------------------------------
__global__ __launch_bounds__(64) void k_v1(const float* __restrict__ em,
    const float* __restrict__ trans, float* __restrict__ pc)
{
  const int c = blockIdx.x, l = threadIdx.x;
  const int ii = l / 5, jj = l % 5;
  const float tc0 = trans[0 * 5 + jj], tc1 = trans[1 * 5 + jj], tc2 = trans[2 * 5 + jj];
  const float tc3 = trans[3 * 5 + jj], tc4 = trans[4 * 5 + jj];
  const int t0 = c * 128 + 1;
  const int t1 = min(t0 + 127, L - 1);
  float M = ((ii < 5) ? trans[ii * 5 + jj] : 0.f) + em[(size_t)t0 * 8 + jj];
  for (int t = t0 + 1; t <= t1; ++t) {
    const float emj = em[(size_t)t * 8 + jj];
    const float m0 = __shfl(M, ii * 5 + 0, 64) + tc0;
    const float m1 = __shfl(M, ii * 5 + 1, 64) + tc1;
    const float m2 = __shfl(M, ii * 5 + 2, 64) + tc2;
    const float m3 = __shfl(M, ii * 5 + 3, 64) + tc3;
    const float m4 = __shfl(M, ii * 5 + 4, 64) + tc4;
    M = fmaxf(fmaxf(fmaxf(m0, m1), fmaxf(m2, m3)), m4) + emj;
  }
  if (l < 25) pc[c * 32 + l] = M;
}

__global__ __launch_bounds__(64) void k_v2(const float* __restrict__ em,
    const float* __restrict__ pc, const float* __restrict__ start_,
    const float* __restrict__ end_, float* __restrict__ sb, int* __restrict__ last_)
{
  __shared__ float lpc[2048];
  const int l = threadIdx.x;
  for (int i = l; i < 2048; i += 64) lpc[i] = pc[i];
  __syncthreads();
  const int jj = (l < 5) ? l : 0;
  float s = start_[jj] + em[jj];
  if (l < 5) sb[l] = s;
  for (int c = 0; c < 64; ++c) {
    const float s0 = __shfl(s, 0, 64), s1 = __shfl(s, 1, 64), s2 = __shfl(s, 2, 64);
    const float s3 = __shfl(s, 3, 64), s4 = __shfl(s, 4, 64);
    s = fmaxf(fmaxf(fmaxf(s0 + lpc[c * 32 + 0 * 5 + jj], s1 + lpc[c * 32 + 1 * 5 + jj]),
                    fmaxf(s2 + lpc[c * 32 + 2 * 5 + jj], s3 + lpc[c * 32 + 3 * 5 + jj])),
              s4 + lpc[c * 32 + 4 * 5 + jj]);
    if (l < 5) sb[(c + 1) * 8 + l] = s;
  }
  const float v = s + end_[jj];
  const float v0 = __shfl(v, 0, 64), v1 = __shfl(v, 1, 64), v2 = __shfl(v, 2, 64);
  const float v3 = __shfl(v, 3, 64), v4 = __shfl(v, 4, 64);
  if (l == 0) {
    float best = v0; int bt = 0;
    if (v1 > best) { best = v1; bt = 1; }
    if (v2 > best) { best = v2; bt = 2; }
    if (v3 > best) { best = v3; bt = 3; }
    if (v4 > best) { best = v4; bt = 4; }
    *last_ = bt;
  }
}

__global__ __launch_bounds__(64) void k_v3(const float* __restrict__ em,
    const float* __restrict__ trans, const float* __restrict__ sb,
    unsigned char* __restrict__ bp)
{
  const int c = blockIdx.x, l = threadIdx.x;
  const int jj = (l < 5) ? l : 0;
  const float tc0 = trans[0 * 5 + jj], tc1 = trans[1 * 5 + jj], tc2 = trans[2 * 5 + jj];
  const float tc3 = trans[3 * 5 + jj], tc4 = trans[4 * 5 + jj];
  float s = sb[c * 8 + jj];
  const int t0 = c * 128 + 1, t1 = min(c * 128 + 128, L - 1);
  for (int t = t0; t <= t1; ++t) {
    const float s0 = __shfl(s, 0, 64), s1 = __shfl(s, 1, 64), s2 = __shfl(s, 2, 64);
    const float s3 = __shfl(s, 3, 64), s4 = __shfl(s, 4, 64);
    float best = s0 + tc0; int bi = 0;
    float cv = s1 + tc1; if (cv > best) { best = cv; bi = 1; }
    cv = s2 + tc2; if (cv > best) { best = cv; bi = 2; }
    cv = s3 + tc3; if (cv > best) { best = cv; bi = 3; }
    cv = s4 + tc4; if (cv > best) { best = cv; bi = 4; }
    if (l < 5) bp[(size_t)t * 5 + jj] = (unsigned char)bi;
    s = best + em[(size_t)t * 8 + jj];
  }
}

__global__ __launch_bounds__(64) void k_v4(const unsigned char* __restrict__ bp,
    unsigned char* __restrict__ F)
{
  __shared__ unsigned char bl[128 * 5];
  const int c = blockIdx.x, l = threadIdx.x;
  const int t0 = c * 128 + 1, t1 = min(c * 128 + 128, L - 1);
  const int n = t1 - t0 + 1;
  for (int i = l; i < n * 5; i += 64) bl[i] = bp[(size_t)t0 * 5 + i];
  __syncthreads();
  if (l < 5) {
    int tag = l;
    for (int t = t1; t >= t0; --t) tag = bl[(t - t0) * 5 + tag];
    F[c * 8 + l] = (unsigned char)tag;
  }
}

__global__ __launch_bounds__(64) void k_v5(const unsigned char* __restrict__ F,
    const int* __restrict__ last_, int* __restrict__ tb)
{
  __shared__ unsigned char lf[512];
  const int l = threadIdx.x;
  for (int i = l; i < 512; i += 64) lf[i] = F[i];
  __syncthreads();
  if (l == 0) {
    int cur = *last_;
    for (int c = 63; c >= 0; --c) { cur = lf[c * 8 + cur]; tb[c] = cur; }
  }
}

__global__ __launch_bounds__(64) void k_v6(const unsigned char* __restrict__ bp,
    const int* __restrict__ tb, const int* __restrict__ last_, int* __restrict__ out)
{
  __shared__ unsigned char bl[128 * 5];
  const int c = blockIdx.x, l = threadIdx.x;
  const int t0 = c * 128 + 1, t1 = min(c * 128 + 128, L - 1);
  const int n = t1 - t0 + 1;
  for (int i = l; i < n * 5; i += 64) bl[i] = bp[(size_t)t0 * 5 + i];
  __syncthreads();
  if (l == 0) {
    int cur = (c == 63) ? *last_ : tb[c + 1];
    if (c == 63) out[L - 1] = cur;
    for (int t = t1; t >= t0; --t) { cur = bl[(t - t0) * 5 + cur]; out[t - 1] = cur; }
  }
}

// ---------------------------------------------------------------------------
extern "C" void kernel_launch(void* const* d_in, const int* in_sizes, int n_in,
                              void* d_out, int out_size, void* d_ws, size_t ws_size,
                              hipStream_t stream)
{
  const int*   sent   = (const int*)d_in[0];
  const float* embed  = (const float*)d_in[1];
  const float* wihf   = (const float*)d_in[2];
  const float* whhf   = (const float*)d_in[3];
  const float* bf     = (const float*)d_in[4];
  const float* wihb   = (const float*)d_in[5];
  const float* whhb   = (const float*)d_in[6];
  const float* bb     = (const float*)d_in[7];
  const float* h0     = (const float*)d_in[8];
  const float* c0     = (const float*)d_in[9];
  const float* wout   = (const float*)d_in[10];
  const float* bout   = (const float*)d_in[11];
  const float* start_ = (const float*)d_in[12];
  const float* end_   = (const float*)d_in[13];
  const float* trans  = (const float*)d_in[14];

  float* ws   = (float*)d_ws;
  float* xp   = ws + XP_OFF;
  float* hs   = ws + HS_OFF;
  float* em   = ws + EM_OFF;
  float* pc   = ws + PC_OFF;
  float* sb   = ws + SB_OFF;
  int*   last_ = (int*)(ws + LAST_OFF);
  unsigned char* bp = (unsigned char*)d_ws + BP_BYTE;
  unsigned char* F  = (unsigned char*)d_ws + F_BYTE;
  int* tb = (int*)((unsigned char*)d_ws + TB_BYTE);
  float* wring = (float*)((unsigned char*)d_ws + WR_BYTE);
  int* out = (int*)d_out;

  // Arm the canaries (0xFF bytes) over hs and the warm rings, every call.
  hipMemsetAsync(hs, 0xFF, (size_t)4194304 * 4, stream);
  hipMemsetAsync(wring, 0xFF, (size_t)128 * WUP * 256 * 4, stream);
  k_xproj<<<dim3(128, 4), 256, 0, stream>>>(sent, embed, wihf, bf, wihb, bb, xp);
  k_lstm <<<128, 512, 0, stream>>>(xp, whhf, whhb, h0, c0, hs, wring);
  k_emis <<<2048, 256, 0, stream>>>(hs, wout, bout, em);
  k_v1   <<<64, 64, 0, stream>>>(em, trans, pc);
  k_v2   <<<1, 64, 0, stream>>>(em, pc, start_, end_, sb, last_);
  k_v3   <<<64, 64, 0, stream>>>(em, trans, sb, bp);
  k_v4   <<<64, 64, 0, stream>>>(bp, F);
  k_v5   <<<1, 64, 0, stream>>>(F, last_, tb);
  k_v6   <<<64, 64, 0, stream>>>(bp, tb, last_, out);
}

// Round 15
// 1031.026 us; speedup vs baseline: 3.0470x; 3.0470x over previous
//
#include <hip/hip_runtime.h>

#define L  8192
#define E  300
#define H  256
#define FH 1024
#define T  5

#define NCH 64     // chunks per direction
#define CHL 128    // owned steps per chunk
#define WUP 48     // warm-up steps (0.5^48 ~ 4e-15 << f32 half-ulp: bit-exact)

typedef float f32x4 __attribute__((ext_vector_type(4)));

// ---- workspace layout (float offsets unless noted) ----
#define XP_OFF   0u           // [2][L][FH]  f32
#define HS_OFF   16777216u    // [2][L][H]   f32  (canary-init each call; polled)
#define EM_OFF   20971520u    // [L][8] f32
#define PC_OFF   21037312u    // [64][32] chunk max-plus matrices (25 used)
#define SB_OFF   21039360u    // [65][8] boundary scores
#define LAST_OFF 21039880u    // int: last tag
#define BP_BYTE  84159552u    // byte offset: [L][5] u8 backpointers
#define F_BYTE   84200512u    // byte offset: [64][8] u8 chunk composition maps
#define TB_BYTE  84201024u    // byte offset: [64] int boundary tags
#define WR_BYTE  84205568u    // byte offset: [128 chunks][WUP][256] f32 warm rings (canary-init)

// 8-lane sum reduction, pure VALU via DPP.
__device__ __forceinline__ float red8(float x) {
  x += __int_as_float(__builtin_amdgcn_update_dpp(0, __float_as_int(x), 0xB1, 0xF, 0xF, true));  // xor 1
  x += __int_as_float(__builtin_amdgcn_update_dpp(0, __float_as_int(x), 0x4E, 0xF, 0xF, true));  // xor 2
  x += __int_as_float(__builtin_amdgcn_update_dpp(0, __float_as_int(x), 0x141, 0xF, 0xF, true)); // half-mirror
  return x;
}

// ---------------------------------------------------------------------------
// Kernel 1: xproj[d][t][r] = bias[d][r] + embed[sent[t]] . W_ih[d][r]
// ---------------------------------------------------------------------------
__global__ __launch_bounds__(256) void k_xproj(
    const int* __restrict__ sent, const float* __restrict__ embed,
    const float* __restrict__ wihf, const float* __restrict__ bf,
    const float* __restrict__ wihb, const float* __restrict__ bb,
    float* __restrict__ xp)
{
  __shared__ float xl[32][304];
  __shared__ int sl[32];
  const int tid = threadIdx.x;
  const int t0 = blockIdx.x * 32;
  const int d = blockIdx.y >> 1, rh = blockIdx.y & 1;
  const int r1 = rh * 256 + tid;     // 0..511
  const int r2 = r1 + 512;           // 512..1023
  if (tid < 32) sl[tid] = sent[t0 + tid];
  __syncthreads();
  for (int tt = 0; tt < 32; ++tt) {
    const float* erow = embed + (size_t)sl[tt] * 300;
    for (int kk = tid; kk < 300; kk += 256) xl[tt][kk] = erow[kk];
  }
  __syncthreads();
  const float* wih  = d ? wihb : wihf;
  const float* bias = d ? bb : bf;
  const float4* wra = (const float4*)(wih + (size_t)r1 * 300);
  const float4* wrb = (const float4*)(wih + (size_t)r2 * 300);
  float acca[32], accb[32];
#pragma unroll
  for (int tt = 0; tt < 32; ++tt) { acca[tt] = 0.f; accb[tt] = 0.f; }
  for (int k4 = 0; k4 < 75; ++k4) {
    const float4 wa = wra[k4];
    const float4 wb = wrb[k4];
#pragma unroll
    for (int tt = 0; tt < 32; ++tt) {
      const float4 xv = *(const float4*)&xl[tt][k4 * 4];
      acca[tt] = fmaf(wa.x, xv.x, fmaf(wa.y, xv.y, fmaf(wa.z, xv.z, fmaf(wa.w, xv.w, acca[tt]))));
      accb[tt] = fmaf(wb.x, xv.x, fmaf(wb.y, xv.y, fmaf(wb.z, xv.z, fmaf(wb.w, xv.w, accb[tt]))));
    }
  }
  const float bv1 = bias[r1], bv2 = bias[r2];
#pragma unroll
  for (int tt = 0; tt < 32; ++tt) {
    xp[((size_t)d * L + (t0 + tt)) * FH + r1] = acca[tt] + bv1;
    xp[((size_t)d * L + (t0 + tt)) * FH + r2] = accb[tt] + bv2;
  }
}

// ---------------------------------------------------------------------------
// Kernel 2: chunked bidirectional LSTM, 4-chunk interleave per block.
// EXACT R13 configuration (measured 791us, absmax 0.0): 32 groups x 4
// slice-blocks (bid = gid + 32*g -> same XCD), 128 blocks. Wave 0 polls
// and publishes (staggered schedule -- round-start polls regress, R14);
// x loads issue before the poll; WUP=48; sc0 producer stores.
// ---------------------------------------------------------------------------
__global__ __launch_bounds__(512, 2) void k_lstm(
    const float* __restrict__ xp,
    const float* __restrict__ whhf, const float* __restrict__ whhb,
    const float* __restrict__ h0, const float* __restrict__ c0,
    float* __restrict__ hs, float* __restrict__ wring)
{
  const int bid = blockIdx.x;
  const int gid = bid & 31;        // group: bid%8 == gid%8 for all 4 slices
  const int g   = bid >> 5;        // slice 0..3: owns units [g*64, g*64+64)
  const int d = gid >> 4, p = gid & 15;
  const int kA = 4 * p, kB = 4 * p + 1, kC = 4 * p + 2, kD = 4 * p + 3;
  const int tid = threadIdx.x;
  const int l = tid & 63, w = tid >> 6;
  const int ul = w * 8 + (l >> 3);   // unit within block 0..63
  const int j  = g * 64 + ul;        // unit 0..255
  const int kq = l & 7;              // this thread covers h[kq*32..+32)
  const float* whh = d ? whhb : whhf;

  // 128 weight floats per thread, pinned via opaque asm.
  float wgf[4][32];
#pragma unroll
  for (int gt = 0; gt < 4; ++gt) {
    const float* base = whh + (size_t)(gt * 256 + j) * 256 + kq * 32;
#pragma unroll
    for (int i = 0; i < 8; ++i) {
      float4 v = *(const float4*)(base + 4 * i);
      asm volatile("" : "+v"(v.x), "+v"(v.y), "+v"(v.z), "+v"(v.w));
      wgf[gt][4 * i + 0] = v.x; wgf[gt][4 * i + 1] = v.y;
      wgf[gt][4 * i + 2] = v.z; wgf[gt][4 * i + 3] = v.w;
    }
  }

  // Per-chunk LDS h broadcast: double-buffered, XOR-swizzled; flag + done-ctr.
  __shared__ float lh[4][2][256];
  __shared__ int lfl[4];
  __shared__ int ldone[4];
  if (tid < 4) { lfl[tid] = 0; ldone[tid] = 0; }
  __syncthreads();

  const bool noWA = (d == 0 && kA == 0);
  const bool noWD = (d == 1 && kD == NCH - 1);
  float cA = noWA ? c0[d * 256 + j] : 0.f;
  float cB = 0.f;
  float cC = 0.f;
  float cD = noWD ? c0[d * 256 + j] : 0.f;

  float* ringA = wring + (size_t)(d * NCH + kA) * (WUP * 256);
  float* ringB = wring + (size_t)(d * NCH + kB) * (WUP * 256);
  float* ringC = wring + (size_t)(d * NCH + kC) * (WUP * 256);
  float* ringD = wring + (size_t)(d * NCH + kD) * (WUP * 256);

  bool slow = false;

  auto chunk_step = [&](int ci, int kch, bool noW, float* ring, float& cst, int r) {
    const int Wc = noW ? 0 : WUP;
    const int sc = noW ? (r - WUP) : r;        // local step index
    if (sc < 0 || sc >= Wc + CHL) return;      // idle round for this chunk
    const int t = d ? (kch * CHL + CHL - 1 + Wc - sc)
                    : (kch * CHL - Wc + sc);

    // this step's x: issued BEFORE the poll; drains under the poll RTT
    const float* xr = xp + ((size_t)d * L + t) * FH;
    const float x0 = xr[j], x1 = xr[256 + j], x2 = xr[512 + j], x3 = xr[768 + j];

    float a0 = 0.f, a1 = 0.f, a2 = 0.f, a3 = 0.f;
    if (sc == 0) {
      if (noW) {     // true h0: stable input, no sync needed
        const float* hp = h0 + d * 256 + kq * 32;
#pragma unroll
        for (int ii = 0; ii < 8; ++ii) {
          const f32x4 hc = *(const f32x4*)(hp + 4 * ii);
#pragma unroll
          for (int dd = 0; dd < 4; ++dd) {
            const float hv = hc[dd];
            a0 = fmaf(wgf[0][4 * ii + dd], hv, a0);
            a1 = fmaf(wgf[1][4 * ii + dd], hv, a1);
            a2 = fmaf(wgf[2][4 * ii + dd], hv, a2);
            a3 = fmaf(wgf[3][4 * ii + dd], hv, a3);
          }
        }
      }
      // else: zero-boot warm start, h == 0 -> a stays 0.
    } else {
      if (w == 0) {
        // ---- wave 0: acquire h(sc-1), publish to LDS ----
        if (sc >= 2) {  // buffer reuse guard: all waves done with step sc-2
          while (__hip_atomic_load(&ldone[ci], __ATOMIC_RELAXED,
                                   __HIP_MEMORY_SCOPE_WORKGROUP) < 8 * (sc - 1)) {}
        }
        const float* src = (sc - 1 < Wc)
            ? (ring + (size_t)(sc - 1) * 256)
            : (hs + ((size_t)d * L + (d ? t + 1 : t - 1)) * H);
        const float* myp = src + 4 * l;
        f32x4 hx;
        int iters = 0;
        for (;;) {
          if (!slow) {
            asm volatile("global_load_dwordx4 %0, %1, off sc0\n\t"
                         "s_waitcnt vmcnt(0)"
                         : "=v"(hx) : "v"(myp) : "memory");
          } else {
            asm volatile("s_sleep 8\n\t"
                         "global_load_dwordx4 %0, %1, off sc0 sc1\n\t"
                         "s_waitcnt vmcnt(0)"
                         : "=v"(hx) : "v"(myp) : "memory");
          }
          const unsigned u0 = __float_as_uint(hx.x), u1 = __float_as_uint(hx.y);
          const unsigned u2 = __float_as_uint(hx.z), u3 = __float_as_uint(hx.w);
          const bool bad = (u0 == 0xFFFFFFFFu) | (u1 == 0xFFFFFFFFu) |
                           (u2 == 0xFFFFFFFFu) | (u3 == 0xFFFFFFFFu);
          if (!__any(bad)) break;
          if (!slow && ++iters > 4096) slow = true;   // sticky fallback (G16)
        }
        const int rr = l >> 3, cc = l & 7;
        *(f32x4*)&lh[ci][sc & 1][rr * 32 + 4 * (cc ^ rr)] = hx;
        asm volatile("s_waitcnt lgkmcnt(0)" ::: "memory");
        __hip_atomic_store(&lfl[ci], sc, __ATOMIC_RELAXED, __HIP_MEMORY_SCOPE_WORKGROUP);
      } else {
        while (__hip_atomic_load(&lfl[ci], __ATOMIC_RELAXED,
                                 __HIP_MEMORY_SCOPE_WORKGROUP) < sc) {}
      }
      // ---- conflict-free swizzled LDS reads + 128 fma ----
#pragma unroll
      for (int ii = 0; ii < 8; ++ii) {
        const f32x4 hc = *(const f32x4*)&lh[ci][sc & 1][kq * 32 + 4 * (ii ^ kq)];
#pragma unroll
        for (int dd = 0; dd < 4; ++dd) {
          const float hv = hc[dd];
          a0 = fmaf(wgf[0][4 * ii + dd], hv, a0);
          a1 = fmaf(wgf[1][4 * ii + dd], hv, a1);
          a2 = fmaf(wgf[2][4 * ii + dd], hv, a2);
          a3 = fmaf(wgf[3][4 * ii + dd], hv, a3);
        }
      }
    }
    a0 = red8(a0); a1 = red8(a1); a2 = red8(a2); a3 = red8(a3);

    const float gi = x0 + a0, gf = x1 + a1, gc = x2 + a2, go = x3 + a3;
    const float ig = 1.f / (1.f + __expf(-gi));
    const float fg = 1.f / (1.f + __expf(-gf));
    const float cg = 1.f - 2.f / (1.f + __expf(2.f * gc));   // tanh
    const float og = 1.f / (1.f + __expf(-go));
    cst = fg * cst + ig * cg;
    const float hn = og * (1.f - 2.f / (1.f + __expf(2.f * cst)));
    if (kq == 0) {
      float* dst = (sc < Wc) ? (ring + (size_t)sc * 256 + j)
                             : (hs + ((size_t)d * L + t) * H + j);
      // sc0 store: write directed at L2 (the handoff coherence point)
      asm volatile("global_store_dword %0, %1, off sc0"
                   :: "v"(dst), "v"(hn) : "memory");
    }
    if (l == 0)
      __hip_atomic_fetch_add(&ldone[ci], 1, __ATOMIC_RELAXED, __HIP_MEMORY_SCOPE_WORKGROUP);
  };

  for (int r = 0; r < WUP + CHL; ++r) {
    chunk_step(0, kA, noWA, ringA, cA, r);
    chunk_step(1, kB, false, ringB, cB, r);
    chunk_step(2, kC, false, ringC, cC, r);
    chunk_step(3, kD, noWD, ringD, cD, r);
    if ((r & 63) == 63) __threadfence();   // rare MALL visibility (G16 fallback)
  }
}

// ---------------------------------------------------------------------------
// Kernel 3: emission[t][tag]
// ---------------------------------------------------------------------------
__global__ __launch_bounds__(256) void k_emis(
    const float* __restrict__ hs, const float* __restrict__ wout,
    const float* __restrict__ bout, float* __restrict__ em)
{
  const int tid = threadIdx.x, l = tid & 63;
  const int t = blockIdx.x * 4 + (tid >> 6);
  const float4 hf = ((const float4*)(hs + (size_t)t * H))[l];
  const float4 hb = ((const float4*)(hs + (size_t)L * H + (size_t)t * H))[l];
  const float4* w4 = (const float4*)wout;
  float s[5];
#pragma unroll
  for (int tag = 0; tag < 5; ++tag) {
    const float4 wf = w4[tag * 128 + l];
    const float4 wb = w4[tag * 128 + 64 + l];
    float p = hf.x * wf.x + hf.y * wf.y + hf.z * wf.z + hf.w * wf.w
            + hb.x * wb.x + hb.y * wb.y + hb.z * wb.z + hb.w * wb.w;
#pragma unroll
    for (int m = 1; m < 64; m <<= 1) p += __shfl_xor(p, m, 64);
    s[tag] = p;
  }
  if (l == 0) {
#pragma unroll
    for (int tag = 0; tag < 5; ++tag) em[(size_t)t * 8 + tag] = s[tag] + bout[tag];
  }
}

// ---------------------------------------------------------------------------
// Viterbi, chunked (64 chunks x 128 transitions), max-plus associativity.
// ---------------------------------------------------------------------------
__global__ __launch_bounds__(64) void k_v1(const float* __restrict__ em,
    const float* __restrict__ trans, float* __restrict__ pc)
{
  const int c = blockIdx.x, l = threadIdx.x;
  const int ii = l / 5, jj = l % 5;
  const float tc0 = trans[0 * 5 + jj], tc1 = trans[1 * 5 + jj], tc2 = trans[2 * 5 + jj];
  const float tc3 = trans[3 * 5 + jj], tc4 = trans[4 * 5 + jj];
  const int t0 = c * 128 + 1;
  const int t1 = min(t0 + 127, L - 1);
  float M = ((ii < 5) ? trans[ii * 5 + jj] : 0.f) + em[(size_t)t0 * 8 + jj];
  for (int t = t0 + 1; t <= t1; ++t) {
    const float emj = em[(size_t)t * 8 + jj];
    const float m0 = __shfl(M, ii * 5 + 0, 64) + tc0;
    const float m1 = __shfl(M, ii * 5 + 1, 64) + tc1;
    const float m2 = __shfl(M, ii * 5 + 2, 64) + tc2;
    const float m3 = __shfl(M, ii * 5 + 3, 64) + tc3;
    const float m4 = __shfl(M, ii * 5 + 4, 64) + tc4;
    M = fmaxf(fmaxf(fmaxf(m0, m1), fmaxf(m2, m3)), m4) + emj;
  }
  if (l < 25) pc[c * 32 + l] = M;
}

__global__ __launch_bounds__(64) void k_v2(const float* __restrict__ em,
    const float* __restrict__ pc, const float* __restrict__ start_,
    const float* __restrict__ end_, float* __restrict__ sb, int* __restrict__ last_)
{
  __shared__ float lpc[2048];
  const int l = threadIdx.x;
  for (int i = l; i < 2048; i += 64) lpc[i] = pc[i];
  __syncthreads();
  const int jj = (l < 5) ? l : 0;
  float s = start_[jj] + em[jj];
  if (l < 5) sb[l] = s;
  for (int c = 0; c < 64; ++c) {
    const float s0 = __shfl(s, 0, 64), s1 = __shfl(s, 1, 64), s2 = __shfl(s, 2, 64);
    const float s3 = __shfl(s, 3, 64), s4 = __shfl(s, 4, 64);
    s = fmaxf(fmaxf(fmaxf(s0 + lpc[c * 32 + 0 * 5 + jj], s1 + lpc[c * 32 + 1 * 5 + jj]),
                    fmaxf(s2 + lpc[c * 32 + 2 * 5 + jj], s3 + lpc[c * 32 + 3 * 5 + jj])),
              s4 + lpc[c * 32 + 4 * 5 + jj]);
    if (l < 5) sb[(c + 1) * 8 + l] = s;
  }
  const float v = s + end_[jj];
  const float v0 = __shfl(v, 0, 64), v1 = __shfl(v, 1, 64), v2 = __shfl(v, 2, 64);
  const float v3 = __shfl(v, 3, 64), v4 = __shfl(v, 4, 64);
  if (l == 0) {
    float best = v0; int bt = 0;
    if (v1 > best) { best = v1; bt = 1; }
    if (v2 > best) { best = v2; bt = 2; }
    if (v3 > best) { best = v3; bt = 3; }
    if (v4 > best) { best = v4; bt = 4; }
    *last_ = bt;
  }
}

__global__ __launch_bounds__(64) void k_v3(const float* __restrict__ em,
    const float* __restrict__ trans, const float* __restrict__ sb,
    unsigned char* __restrict__ bp)
{
  const int c = blockIdx.x, l = threadIdx.x;
  const int jj = (l < 5) ? l : 0;
  const float tc0 = trans[0 * 5 + jj], tc1 = trans[1 * 5 + jj], tc2 = trans[2 * 5 + jj];
  const float tc3 = trans[3 * 5 + jj], tc4 = trans[4 * 5 + jj];
  float s = sb[c * 8 + jj];
  const int t0 = c * 128 + 1, t1 = min(c * 128 + 128, L - 1);
  for (int t = t0; t <= t1; ++t) {
    const float s0 = __shfl(s, 0, 64), s1 = __shfl(s, 1, 64), s2 = __shfl(s, 2, 64);
    const float s3 = __shfl(s, 3, 64), s4 = __shfl(s, 4, 64);
    float best = s0 + tc0; int bi = 0;
    float cv = s1 + tc1; if (cv > best) { best = cv; bi = 1; }
    cv = s2 + tc2; if (cv > best) { best = cv; bi = 2; }
    cv = s3 + tc3; if (cv > best) { best = cv; bi = 3; }
    cv = s4 + tc4; if (cv > best) { best = cv; bi = 4; }
    if (l < 5) bp[(size_t)t * 5 + jj] = (unsigned char)bi;
    s = best + em[(size_t)t * 8 + jj];
  }
}

__global__ __launch_bounds__(64) void k_v4(const unsigned char* __restrict__ bp,
    unsigned char* __restrict__ F)
{
  __shared__ unsigned char bl[128 * 5];
  const int c = blockIdx.x, l = threadIdx.x;
  const int t0 = c * 128 + 1, t1 = min(c * 128 + 128, L - 1);
  const int n = t1 - t0 + 1;
  for (int i = l; i < n * 5; i += 64) bl[i] = bp[(size_t)t0 * 5 + i];
  __syncthreads();
  if (l < 5) {
    int tag = l;
    for (int t = t1; t >= t0; --t) tag = bl[(t - t0) * 5 + tag];
    F[c * 8 + l] = (unsigned char)tag;
  }
}

__global__ __launch_bounds__(64) void k_v5(const unsigned char* __restrict__ F,
    const int* __restrict__ last_, int* __restrict__ tb)
{
  __shared__ unsigned char lf[512];
  const int l = threadIdx.x;
  for (int i = l; i < 512; i += 64) lf[i] = F[i];
  __syncthreads();
  if (l == 0) {
    int cur = *last_;
    for (int c = 63; c >= 0; --c) { cur = lf[c * 8 + cur]; tb[c] = cur; }
  }
}

__global__ __launch_bounds__(64) void k_v6(const unsigned char* __restrict__ bp,
    const int* __restrict__ tb, const int* __restrict__ last_, int* __restrict__ out)
{
  __shared__ unsigned char bl[128 * 5];
  const int c = blockIdx.x, l = threadIdx.x;
  const int t0 = c * 128 + 1, t1 = min(c * 128 + 128, L - 1);
  const int n = t1 - t0 + 1;
  for (int i = l; i < n * 5; i += 64) bl[i] = bp[(size_t)t0 * 5 + i];
  __syncthreads();
  if (l == 0) {
    int cur = (c == 63) ? *last_ : tb[c + 1];
    if (c == 63) out[L - 1] = cur;
    for (int t = t1; t >= t0; --t) { cur = bl[(t - t0) * 5 + cur]; out[t - 1] = cur; }
  }
}

// ---------------------------------------------------------------------------
extern "C" void kernel_launch(void* const* d_in, const int* in_sizes, int n_in,
                              void* d_out, int out_size, void* d_ws, size_t ws_size,
                              hipStream_t stream)
{
  const int*   sent   = (const int*)d_in[0];
  const float* embed  = (const float*)d_in[1];
  const float* wihf   = (const float*)d_in[2];
  const float* whhf   = (const float*)d_in[3];
  const float* bf     = (const float*)d_in[4];
  const float* wihb   = (const float*)d_in[5];
  const float* whhb   = (const float*)d_in[6];
  const float* bb     = (const float*)d_in[7];
  const float* h0     = (const float*)d_in[8];
  const float* c0     = (const float*)d_in[9];
  const float* wout   = (const float*)d_in[10];
  const float* bout   = (const float*)d_in[11];
  const float* start_ = (const float*)d_in[12];
  const float* end_   = (const float*)d_in[13];
  const float* trans  = (const float*)d_in[14];

  float* ws   = (float*)d_ws;
  float* xp   = ws + XP_OFF;
  float* hs   = ws + HS_OFF;
  float* em   = ws + EM_OFF;
  float* pc   = ws + PC_OFF;
  float* sb   = ws + SB_OFF;
  int*   last_ = (int*)(ws + LAST_OFF);
  unsigned char* bp = (unsigned char*)d_ws + BP_BYTE;
  unsigned char* F  = (unsigned char*)d_ws + F_BYTE;
  int* tb = (int*)((unsigned char*)d_ws + TB_BYTE);
  float* wring = (float*)((unsigned char*)d_ws + WR_BYTE);
  int* out = (int*)d_out;

  // Arm the canaries (0xFF bytes) over hs and the warm rings, every call.
  hipMemsetAsync(hs, 0xFF, (size_t)4194304 * 4, stream);
  hipMemsetAsync(wring, 0xFF, (size_t)128 * WUP * 256 * 4, stream);
  k_xproj<<<dim3(256, 4), 256, 0, stream>>>(sent, embed, wihf, bf, wihb, bb, xp);
  k_lstm <<<128, 512, 0, stream>>>(xp, whhf, whhb, h0, c0, hs, wring);
  k_emis <<<2048, 256, 0, stream>>>(hs, wout, bout, em);
  k_v1   <<<64, 64, 0, stream>>>(em, trans, pc);
  k_v2   <<<1, 64, 0, stream>>>(em, pc, start_, end_, sb, last_);
  k_v3   <<<64, 64, 0, stream>>>(em, trans, sb, bp);
  k_v4   <<<64, 64, 0, stream>>>(bp, F);
  k_v5   <<<1, 64, 0, stream>>>(F, last_, tb);
  k_v6   <<<64, 64, 0, stream>>>(bp, tb, last_, out);
}